// Round 2
// baseline (13125.217 us; speedup 1.0000x reference)
//
#include <hip/hip_runtime.h>
#include <hip/hip_bf16.h>
#include <hip/hip_cooperative_groups.h>

namespace cg = cooperative_groups;

#define SEQ_   128
#define NCLS_  50257
#define EMB_   1024
#define HID_   1024
#define BATCH_ 1024
#define G4_    4096

typedef __attribute__((ext_vector_type(8))) short short8;
typedef __attribute__((ext_vector_type(4))) float f32x4;

__device__ __forceinline__ void async_copy16(void* lds, const void* g) {
  __builtin_amdgcn_global_load_lds(
      (const __attribute__((address_space(1))) void*)g,
      (__attribute__((address_space(3))) void*)lds, 16, 0, 0);
}

__device__ __forceinline__ void mfma_acc(f32x4& c, const short8& a, const short8& b) {
  asm("v_mfma_f32_16x16x32_bf16 %0, %1, %2, %0" : "+v"(c) : "v"(a), "v"(b));
}

__device__ __forceinline__ float sigmoidf_(float x) {
  return 1.f / (1.f + __expf(-x));
}
__device__ __forceinline__ float tanhf_(float x) {
  x = fminf(12.f, fmaxf(-12.f, x));
  float e = __expf(2.f * x);
  return (e - 1.f) / (e + 1.f);
}
__device__ __forceinline__ float bf2f_(ushort u) {
  return __uint_as_float(((unsigned int)u) << 16);
}

// ---------------------------------------------------------------------------
// MFMA GEMM: C[M,N] = A[M,K](bf16 rm) x Bt[N,K](bf16 rm), fp32 acc.
// EPI 0: outB = bf16(acc + bias0[col])   (E_proj; bias pre-permuted)
// EPI 2: outF = acc + bias0[col]         (logits)
// ---------------------------------------------------------------------------
template <int EPI>
__global__ __launch_bounds__(256) void gemm_bt(
    const __hip_bfloat16* __restrict__ A, const __hip_bfloat16* __restrict__ Bt,
    float* __restrict__ outF, __hip_bfloat16* __restrict__ outB,
    int Mreal, int Nreal, int K, long ostride,
    const float* __restrict__ bias0) {
  __shared__ __align__(16) __hip_bfloat16 lA[128 * 32];
  __shared__ __align__(16) __hip_bfloat16 lB[128 * 32];

  const int tid = threadIdx.x;
  const int lane = tid & 63;
  const int w = tid >> 6;
  const int wm = w >> 1;
  const int wn = w & 1;
  const int m0 = blockIdx.y * 128;
  const int n0 = blockIdx.x * 128;

  f32x4 acc[4][4];
#pragma unroll
  for (int i = 0; i < 4; ++i)
#pragma unroll
    for (int j = 0; j < 4; ++j) acc[i][j] = (f32x4)(0.0f);

  for (int k0 = 0; k0 < K; k0 += 32) {
#pragma unroll
    for (int i = 0; i < 2; ++i) {
      const int chunk = w * 128 + i * 64 + lane;
      const int row = chunk >> 2;
      const int kb = (chunk & 3) * 16;
      long ar = m0 + row; if (ar >= Mreal) ar = Mreal - 1;
      async_copy16((char*)lA + w * 2048 + i * 1024,
                   (const char*)A + (ar * (long)K + k0) * 2 + kb);
      long br = n0 + row; if (br >= Nreal) br = Nreal - 1;
      async_copy16((char*)lB + w * 2048 + i * 1024,
                   (const char*)Bt + (br * (long)K + k0) * 2 + kb);
    }
    __syncthreads();

    const int kk = (lane >> 4) * 8;
    const int fr = lane & 15;
    short8 aF[4], bF[4];
#pragma unroll
    for (int f = 0; f < 4; ++f) {
      aF[f] = *(const short8*)((const char*)lA + ((wm * 64 + f * 16 + fr) * 32 + kk) * 2);
      bF[f] = *(const short8*)((const char*)lB + ((wn * 64 + f * 16 + fr) * 32 + kk) * 2);
    }
#pragma unroll
    for (int fm = 0; fm < 4; ++fm)
#pragma unroll
      for (int fn = 0; fn < 4; ++fn) mfma_acc(acc[fm][fn], aF[fm], bF[fn]);
    __syncthreads();
  }

  const int cn = lane & 15;
  const int rb = (lane >> 4) * 4;
#pragma unroll
  for (int fn = 0; fn < 4; ++fn) {
    const int col = n0 + wn * 64 + fn * 16 + cn;
    const float badd = (col < Nreal) ? bias0[col] : 0.f;
#pragma unroll
    for (int fm = 0; fm < 4; ++fm) {
#pragma unroll
      for (int r = 0; r < 4; ++r) {
        const int row = m0 + wm * 64 + fm * 16 + rb + r;
        const float v = acc[fm][fn][r] + badd;
        if (EPI == 0) {
          if (row < Mreal) outB[(long)row * ostride + col] = __float2bfloat16(v);
        } else {
          if (col < Nreal && row < Mreal) outF[(long)row * ostride + col] = v;
        }
      }
    }
  }
}

// ---------------------------------------------------------------------------
// Persistent cooperative LSTM. 256 blocks x 512 threads (8 waves).
// Block: 128 batch-rows x 128 gate-cols (32 h, col = 4h+g interleaved).
// 8 waves = 2x2 grid of 64x64 tiles x 2 K-halves; partials merged in LDS.
// Whr [4096][1024]: gate-interleaved rows, k XOR-swizzled per 64-group.
// hbuf [2][1024][1024] bf16, same k-swizzle (this kernel writes it).
// ---------------------------------------------------------------------------
__global__ __launch_bounds__(512, 2) void lstm_persist(
    const __hip_bfloat16* __restrict__ Whr,
    const __hip_bfloat16* __restrict__ Epr,
    const int* __restrict__ X,
    __hip_bfloat16* __restrict__ hbuf,
    __hip_bfloat16* __restrict__ hfin) {
  // staging A0|A1|B0|B1 (4 x 16 KB) unioned with gacc[128][132] f32 (67.6 KB)
  __shared__ __align__(16) char smem[128 * 132 * 4];
  float* gacc = (float*)smem;

  const int tid = threadIdx.x;
  const int lane = tid & 63;
  const int w = tid >> 6;
  const int wm = (w >> 1) & 1;
  const int wn = w & 1;
  const int kh = w >> 2;
  const int bid = blockIdx.x;
  const int ct = bid & 31;   // XCD = bid%8 = ct%8 -> Wh slice L2-resident
  const int mt = bid >> 5;
  const int m0 = mt * 128;
  const int n0 = ct * 128;

  const int fr = lane & 15;
  const int cn = lane & 15;
  const int rb = (lane >> 4) * 4;
  const int kbyte = kh * 64 + (lane >> 4) * 16;
  const int swz = (fr & 7) << 4;

  const int crow = tid >> 2;  // cell phase: 0..127
  const int hq = tid & 3;

  float cst[8];
#pragma unroll
  for (int j = 0; j < 8; ++j) cst[j] = 0.f;

  cg::grid_group grid = cg::this_grid();

  for (int t = 0; t < SEQ_; ++t) {
    const __hip_bfloat16* hcur = hbuf + (size_t)(t & 1) * (1024 * 1024);
    __hip_bfloat16* hnxt = hbuf + (size_t)((t + 1) & 1) * (1024 * 1024);
    const __hip_bfloat16* gA = hcur + (size_t)m0 * 1024;
    const __hip_bfloat16* gB = Whr + (size_t)n0 * 1024;

    f32x4 acc[4][4];
#pragma unroll
    for (int i = 0; i < 4; ++i)
#pragma unroll
      for (int j = 0; j < 4; ++j) acc[i][j] = (f32x4)(0.0f);

    // prologue: stage chunk 0 -> buf 0
#pragma unroll
    for (int q = 0; q < 4; ++q) {
      const int ridx = (q & 1) * 512 + tid;
      const __hip_bfloat16* src = (q < 2 ? gA : gB) + (ridx >> 3) * 1024 + (ridx & 7) * 8;
      char* dst = smem + (q < 2 ? 0 : 32768) + (((q & 1) * 512 + w * 64) * 16);
      async_copy16(dst, src);
    }

    for (int kc = 0; kc < 16; ++kc) {
      const int b = kc & 1;
      if (kc < 15) {
#pragma unroll
        for (int q = 0; q < 4; ++q) {
          const int ridx = (q & 1) * 512 + tid;
          const __hip_bfloat16* src =
              (q < 2 ? gA : gB) + (ridx >> 3) * 1024 + (kc + 1) * 64 + (ridx & 7) * 8;
          char* dst = smem + (q < 2 ? 0 : 32768) + (b ^ 1) * 16384 +
                      (((q & 1) * 512 + w * 64) * 16);
          async_copy16(dst, src);
        }
        asm volatile("s_waitcnt vmcnt(4)" ::: "memory");
      } else {
        asm volatile("s_waitcnt vmcnt(0)" ::: "memory");
      }
      __builtin_amdgcn_s_barrier();
      __builtin_amdgcn_sched_barrier(0);

      short8 aR[4], bR[4];
#pragma unroll
      for (int f = 0; f < 4; ++f) {
        const int ar = wm * 64 + f * 16 + fr;
        aR[f] = *(const short8*)(smem + b * 16384 + ar * 128 + (kbyte ^ swz));
        const int br = wn * 64 + f * 16 + fr;
        bR[f] = *(const short8*)(smem + 32768 + b * 16384 + br * 128 + (kbyte ^ swz));
      }
#pragma unroll
      for (int i = 0; i < 4; ++i)
#pragma unroll
        for (int j = 0; j < 4; ++j) mfma_acc(acc[i][j], aR[i], bR[j]);

      __builtin_amdgcn_sched_barrier(0);
      __builtin_amdgcn_s_barrier();
    }

    // ---- merge K-half partials in LDS (gacc aliases dead staging bufs)
    if (kh == 0) {
#pragma unroll
      for (int i = 0; i < 4; ++i)
#pragma unroll
        for (int j = 0; j < 4; ++j)
#pragma unroll
          for (int r = 0; r < 4; ++r)
            gacc[(wm * 64 + i * 16 + rb + r) * 132 + wn * 64 + j * 16 + cn] =
                acc[i][j][r];
    }
    __syncthreads();
    if (kh == 1) {
#pragma unroll
      for (int i = 0; i < 4; ++i)
#pragma unroll
        for (int j = 0; j < 4; ++j)
#pragma unroll
          for (int r = 0; r < 4; ++r)
            gacc[(wm * 64 + i * 16 + rb + r) * 132 + wn * 64 + j * 16 + cn] +=
                acc[i][j][r];
    }
    __syncthreads();

    // ---- fused LSTM cell. thread -> (crow, h block of 8)
    const int tok = X[(m0 + crow) * SEQ_ + t];
    const __hip_bfloat16* ep = Epr + (size_t)tok * G4_ + n0 + hq * 32;
    short8 e[4];
    e[0] = *(const short8*)(ep);
    e[1] = *(const short8*)(ep + 8);
    e[2] = *(const short8*)(ep + 16);
    e[3] = *(const short8*)(ep + 24);
    const float* grow = gacc + crow * 132 + hq * 32;
    short8 hv;
#pragma unroll
    for (int j = 0; j < 8; ++j) {
      const f32x4 g4 = *(const f32x4*)(grow + j * 4);
      const short8 ev = e[j >> 1];
      const int b4 = (j & 1) * 4;
      const float iv = sigmoidf_(g4[0] + bf2f_((ushort)ev[b4 + 0]));
      const float fv = sigmoidf_(g4[1] + bf2f_((ushort)ev[b4 + 1]));
      const float gv = tanhf_(g4[2] + bf2f_((ushort)ev[b4 + 2]));
      const float ov = sigmoidf_(g4[3] + bf2f_((ushort)ev[b4 + 3]));
      cst[j] = fv * cst[j] + iv * gv;
      const float hval = ov * tanhf_(cst[j]);
      __hip_bfloat16 hb = __float2bfloat16(hval);
      hv[j] = *reinterpret_cast<short*>(&hb);
    }
    const int hcol = ct * 32 + hq * 8;
    const int hsw = (hcol & ~63) | ((hcol & 63) ^ ((crow & 7) * 8));
    *(short8*)(hnxt + (size_t)(m0 + crow) * 1024 + hsw) = hv;
    if (t == SEQ_ - 1)
      *(short8*)(hfin + (size_t)(m0 + crow) * 1024 + hcol) = hv;

    __threadfence();
    grid.sync();
  }
}

// fp32 -> bf16 flat convert
__global__ __launch_bounds__(256) void conv_bf16_k(const float* __restrict__ in,
                                                   __hip_bfloat16* __restrict__ out, int n4) {
  const int i = blockIdx.x * 256 + threadIdx.x;
  if (i >= n4) return;
  const float4 v = ((const float4*)in)[i];
  const int o = i * 4;
  out[o + 0] = __float2bfloat16(v.x);
  out[o + 1] = __float2bfloat16(v.y);
  out[o + 2] = __float2bfloat16(v.z);
  out[o + 3] = __float2bfloat16(v.w);
}

// in[R][C] fp32 -> out bf16 [C][R]-ish with optional gate-perm of rows and
// XOR-swizzle of cols (for the persistent kernel's staged reads).
template <bool PERM, bool SWZ>
__global__ __launch_bounds__(256) void transpose_conv(const float* __restrict__ in,
                                                      __hip_bfloat16* __restrict__ out,
                                                      int R, int C) {
  __shared__ float tile[32][33];
  const int c0 = blockIdx.x * 32, r0 = blockIdx.y * 32;
  const int tx = threadIdx.x, ty = threadIdx.y;  // 32x8
#pragma unroll
  for (int i = 0; i < 4; ++i) {
    const int r = r0 + ty + i * 8, cc = c0 + tx;
    tile[ty + i * 8][tx] = (r < R && cc < C) ? in[(size_t)r * C + cc] : 0.f;
  }
  __syncthreads();
#pragma unroll
  for (int i = 0; i < 4; ++i) {
    const int ro = c0 + ty + i * 8, co = r0 + tx;
    if (ro < C && co < R) {
      const int n = PERM ? ((ro & 1023) * 4 + (ro >> 10)) : ro;
      int k = co;
      if (SWZ) k = (k & ~63) | ((k & 63) ^ ((n & 7) * 8));
      out[(size_t)n * R + k] = __float2bfloat16(tile[tx][ty + i * 8]);
    }
  }
}

// bP[4h+g] = bx[g*1024+h] + bh[g*1024+h]
__global__ __launch_bounds__(256) void bias_perm(const float* __restrict__ bx,
                                                 const float* __restrict__ bh,
                                                 float* __restrict__ bP) {
  const int n = blockIdx.x * 256 + threadIdx.x;
  if (n >= G4_) return;
  const int h = n >> 2, g = n & 3;
  bP[n] = bx[g * HID_ + h] + bh[g * HID_ + h];
}

extern "C" void kernel_launch(void* const* d_in, const int* in_sizes, int n_in,
                              void* d_out, int out_size, void* d_ws, size_t ws_size,
                              hipStream_t stream) {
  const int* X = (const int*)d_in[0];
  const float* C = (const float*)d_in[1];
  const float* Wx = (const float*)d_in[2];
  const float* bx = (const float*)d_in[3];
  const float* Wh = (const float*)d_in[4];
  const float* bh = (const float*)d_in[5];
  const float* Wo = (const float*)d_in[6];
  const float* bo = (const float*)d_in[7];
  float* out = (float*)d_out;

  char* p = (char*)d_ws;
  const size_t szCb  = (size_t)NCLS_ * EMB_ * 2;   // Cb, reused for Wot
  const size_t szWxt = (size_t)G4_ * EMB_ * 2;
  const size_t szWht = (size_t)G4_ * HID_ * 2;
  const size_t szEpr = (size_t)NCLS_ * G4_ * 2;
  const size_t szHb  = (size_t)2 * BATCH_ * HID_ * 2;
  const size_t szHf  = (size_t)BATCH_ * HID_ * 2;
  const size_t szBp  = (size_t)G4_ * 4;
  if (ws_size < szCb + szWxt + szWht + szEpr + szHb + szHf + szBp) return;

  __hip_bfloat16* Cb   = (__hip_bfloat16*)p; p += szCb;
  __hip_bfloat16* WxtP = (__hip_bfloat16*)p; p += szWxt;
  __hip_bfloat16* Whr  = (__hip_bfloat16*)p; p += szWht;
  __hip_bfloat16* Epr  = (__hip_bfloat16*)p; p += szEpr;
  __hip_bfloat16* hbuf = (__hip_bfloat16*)p; p += szHb;
  __hip_bfloat16* hfin = (__hip_bfloat16*)p; p += szHf;
  float* bP            = (float*)p;          p += szBp;

  // 1. C -> bf16
  {
    const int n4 = NCLS_ * EMB_ / 4;
    conv_bf16_k<<<(n4 + 255) / 256, 256, 0, stream>>>(C, Cb, n4);
  }
  // 2. Wx -> [4096][1024] gate-perm (no swizzle: consumed by gemm_bt)
  transpose_conv<true, false><<<dim3(G4_ / 32, EMB_ / 32), dim3(32, 8), 0, stream>>>(
      Wx, WxtP, EMB_, G4_);
  // 3. Wh -> [4096][1024] gate-perm + k-swizzle (consumed by lstm_persist)
  transpose_conv<true, true><<<dim3(G4_ / 32, HID_ / 32), dim3(32, 8), 0, stream>>>(
      Wh, Whr, HID_, G4_);
  // 4. permuted bias
  bias_perm<<<G4_ / 256, 256, 0, stream>>>(bx, bh, bP);

  // 5. Epr[V][4096] = C @ Wx (gate-interleaved) + (bx+bh)
  gemm_bt<0><<<dim3(G4_ / 128, (NCLS_ + 127) / 128), 256, 0, stream>>>(
      Cb, WxtP, nullptr, Epr, NCLS_, G4_, EMB_, G4_, bP);

  // 6. zero h[0]
  hipMemsetAsync(hbuf, 0, (size_t)BATCH_ * HID_ * 2, stream);

  // 7. persistent LSTM (all 128 steps, cooperative)
  {
    void* kargs[] = {(void*)&Whr, (void*)&Epr, (void*)&X, (void*)&hbuf, (void*)&hfin};
    hipLaunchCooperativeKernel((void*)lstm_persist, dim3(256), dim3(512), kargs, 0,
                               stream);
  }

  // 8. W_out^T (plain) into Cb region (dead after step 5)
  __hip_bfloat16* Wot = Cb;
  transpose_conv<false, false><<<dim3((NCLS_ + 31) / 32, HID_ / 32), dim3(32, 8), 0,
                                 stream>>>(Wo, Wot, HID_, NCLS_);

  // 9. logits = hfin @ W_out + b_out
  gemm_bt<2><<<dim3((NCLS_ + 127) / 128, BATCH_ / 128), 256, 0, stream>>>(
      hfin, Wot, out, nullptr, BATCH_, NCLS_, HID_, NCLS_, bo);
}

// Round 3
// 4019.066 us; speedup vs baseline: 3.2657x; 3.2657x over previous
//
#include <hip/hip_runtime.h>
#include <hip/hip_bf16.h>

#define SEQ_   128
#define NCLS_  50257
#define EMB_   1024
#define HID_   1024
#define BATCH_ 1024
#define G4_    4096

typedef __attribute__((ext_vector_type(8))) short short8;
typedef __attribute__((ext_vector_type(4))) float f32x4;

__device__ __forceinline__ void async_copy16(void* lds, const void* g) {
  __builtin_amdgcn_global_load_lds(
      (const __attribute__((address_space(1))) void*)g,
      (__attribute__((address_space(3))) void*)lds, 16, 0, 0);
}

__device__ __forceinline__ void mfma_acc(f32x4& c, const short8& a, const short8& b) {
  asm("v_mfma_f32_16x16x32_bf16 %0, %1, %2, %0" : "+v"(c) : "v"(a), "v"(b));
}

__device__ __forceinline__ float sigmoidf_(float x) {
  return 1.f / (1.f + __expf(-x));
}
__device__ __forceinline__ float tanhf_(float x) {
  x = fminf(12.f, fmaxf(-12.f, x));
  float e = __expf(2.f * x);
  return (e - 1.f) / (e + 1.f);
}
__device__ __forceinline__ float bf2f_(ushort u) {
  return __uint_as_float(((unsigned int)u) << 16);
}

// ---------------------------------------------------------------------------
// MFMA GEMM: C[M,N] = A[M,K](bf16 rm) x Bt[N,K](bf16 rm), fp32 acc.
// EPI 0: outB = bf16(acc + bias0[col])   (E_proj; bias pre-permuted)
// EPI 2: outF = acc + bias0[col]         (logits)
// ---------------------------------------------------------------------------
template <int EPI>
__global__ __launch_bounds__(256) void gemm_bt(
    const __hip_bfloat16* __restrict__ A, const __hip_bfloat16* __restrict__ Bt,
    float* __restrict__ outF, __hip_bfloat16* __restrict__ outB,
    int Mreal, int Nreal, int K, long ostride,
    const float* __restrict__ bias0) {
  __shared__ __align__(16) __hip_bfloat16 lA[128 * 32];
  __shared__ __align__(16) __hip_bfloat16 lB[128 * 32];

  const int tid = threadIdx.x;
  const int lane = tid & 63;
  const int w = tid >> 6;
  const int wm = w >> 1;
  const int wn = w & 1;
  const int m0 = blockIdx.y * 128;
  const int n0 = blockIdx.x * 128;

  f32x4 acc[4][4];
#pragma unroll
  for (int i = 0; i < 4; ++i)
#pragma unroll
    for (int j = 0; j < 4; ++j) acc[i][j] = (f32x4)(0.0f);

  for (int k0 = 0; k0 < K; k0 += 32) {
#pragma unroll
    for (int i = 0; i < 2; ++i) {
      const int chunk = w * 128 + i * 64 + lane;
      const int row = chunk >> 2;
      const int kb = (chunk & 3) * 16;
      long ar = m0 + row; if (ar >= Mreal) ar = Mreal - 1;
      async_copy16((char*)lA + w * 2048 + i * 1024,
                   (const char*)A + (ar * (long)K + k0) * 2 + kb);
      long br = n0 + row; if (br >= Nreal) br = Nreal - 1;
      async_copy16((char*)lB + w * 2048 + i * 1024,
                   (const char*)Bt + (br * (long)K + k0) * 2 + kb);
    }
    __syncthreads();

    const int kk = (lane >> 4) * 8;
    const int fr = lane & 15;
    short8 aF[4], bF[4];
#pragma unroll
    for (int f = 0; f < 4; ++f) {
      aF[f] = *(const short8*)((const char*)lA + ((wm * 64 + f * 16 + fr) * 32 + kk) * 2);
      bF[f] = *(const short8*)((const char*)lB + ((wn * 64 + f * 16 + fr) * 32 + kk) * 2);
    }
#pragma unroll
    for (int fm = 0; fm < 4; ++fm)
#pragma unroll
      for (int fn = 0; fn < 4; ++fn) mfma_acc(acc[fm][fn], aF[fm], bF[fn]);
    __syncthreads();
  }

  const int cn = lane & 15;
  const int rb = (lane >> 4) * 4;
#pragma unroll
  for (int fn = 0; fn < 4; ++fn) {
    const int col = n0 + wn * 64 + fn * 16 + cn;
    const float badd = (col < Nreal) ? bias0[col] : 0.f;
#pragma unroll
    for (int fm = 0; fm < 4; ++fm) {
#pragma unroll
      for (int r = 0; r < 4; ++r) {
        const int row = m0 + wm * 64 + fm * 16 + rb + r;
        const float v = acc[fm][fn][r] + badd;
        if (EPI == 0) {
          if (row < Mreal) outB[(long)row * ostride + col] = __float2bfloat16(v);
        } else {
          if (col < Nreal && row < Mreal) outF[(long)row * ostride + col] = v;
        }
      }
    }
  }
}

// ---------------------------------------------------------------------------
// Fused LSTM step (one launch per t). Grid 256 (8 mt x 32 ht), 256 threads.
// Block: 128 batch-rows x 32 h-cols x ALL 4 gates.
// Waves (wm,wn): 64 rows x 16 h; fn indexes the GATE (same 16 h per wave),
// so each lane holds i,f,g,o for its (row, h) -> cell fused, no exchange.
// hprev/Whs are k-XOR-swizzled in global; staged linearly; reads unswizzle.
// Token/Eps/c loads issued BEFORE the K-loop to hide HBM gather latency.
// ---------------------------------------------------------------------------
__global__ __launch_bounds__(256) void lstm_step(
    const __hip_bfloat16* __restrict__ hprev,   // [1024][1024] swizzled
    const __hip_bfloat16* __restrict__ Whs,     // [4096][1024] swizzled
    const __hip_bfloat16* __restrict__ Epr,     // [V][4096] col=4h+g
    const int* __restrict__ X,
    float* __restrict__ cbuf,                   // [1024][1024] f32
    __hip_bfloat16* __restrict__ hnext,         // swizzled
    __hip_bfloat16* __restrict__ hfin,          // plain (last step only)
    int t, int last) {
  __shared__ __align__(16) char smem[32768];    // lA 16K | lB 16K

  const int tid = threadIdx.x;
  const int lane = tid & 63;
  const int w = tid >> 6;
  const int wm = w >> 1;
  const int wn = w & 1;
  const int bid = blockIdx.x;
  const int xcd = bid & 7;
  const int j = bid >> 3;
  const int ht = xcd * 4 + (j & 3);   // same ht group stays on one XCD
  const int mt = j >> 2;
  const int m0 = mt * 128;
  const int h0 = ht * 32;

  const int fr = lane & 15;
  const int cn = lane & 15;
  const int rb = (lane >> 4) * 4;
  const int kb = (lane >> 4) * 16;
  const int swz = (fr & 7) << 4;
  const int hcol = h0 + wn * 16 + cn;

  // ---- prefetch: tokens -> Eps rows (i,f,g,o interleaved) + c state
  int tok[16];
#pragma unroll
  for (int fm = 0; fm < 4; ++fm)
#pragma unroll
    for (int r = 0; r < 4; ++r) {
      const int row = m0 + wm * 64 + fm * 16 + rb + r;
      tok[fm * 4 + r] = X[row * SEQ_ + t];
    }
  ushort4 ep[16];
  float cold[16];
#pragma unroll
  for (int fm = 0; fm < 4; ++fm)
#pragma unroll
    for (int r = 0; r < 4; ++r) {
      const int idx = fm * 4 + r;
      const int row = m0 + wm * 64 + fm * 16 + rb + r;
      ep[idx] = *(const ushort4*)(Epr + (size_t)tok[idx] * G4_ + 4 * hcol);
      cold[idx] = cbuf[(size_t)row * HID_ + hcol];
    }

  f32x4 acc[4][4];  // [fm][gate]
#pragma unroll
  for (int i = 0; i < 4; ++i)
#pragma unroll
    for (int g = 0; g < 4; ++g) acc[i][g] = (f32x4)(0.0f);

  for (int kc = 0; kc < 16; ++kc) {
    // stage A (128 rows x 128B) and B (4 gates x 32 h rows x 128B)
#pragma unroll
    for (int i = 0; i < 8; ++i) {
      const int ridx = i * 256 + tid;        // 0..2047
      const int rt = (ridx >> 3) & 127;
      const int slot = ridx & 7;
      const __hip_bfloat16* src;
      if (i < 4) {
        src = hprev + (size_t)(m0 + rt) * HID_ + kc * 64 + slot * 8;
      } else {
        const int g = rt >> 5, hh = rt & 31;
        src = Whs + (size_t)(g * 1024 + h0 + hh) * HID_ + kc * 64 + slot * 8;
      }
      async_copy16(smem + ridx * 16, src);
    }
    __syncthreads();

    short8 aR[2][4], bR[2][4];
#pragma unroll
    for (int kk = 0; kk < 2; ++kk)
#pragma unroll
      for (int f = 0; f < 4; ++f) {
        aR[kk][f] = *(const short8*)(smem + (wm * 64 + f * 16 + fr) * 128 +
                                     ((kk * 64 + kb) ^ swz));
        bR[kk][f] = *(const short8*)(smem + 16384 + (f * 32 + wn * 16 + fr) * 128 +
                                     ((kk * 64 + kb) ^ swz));
      }
#pragma unroll
    for (int fm = 0; fm < 4; ++fm)
#pragma unroll
      for (int g = 0; g < 4; ++g) {
        mfma_acc(acc[fm][g], aR[0][fm], bR[0][g]);
        mfma_acc(acc[fm][g], aR[1][fm], bR[1][g]);
      }
    __syncthreads();
  }

  // ---- fused cell epilogue
#pragma unroll
  for (int fm = 0; fm < 4; ++fm) {
#pragma unroll
    for (int r = 0; r < 4; ++r) {
      const int idx = fm * 4 + r;
      const int row = m0 + wm * 64 + fm * 16 + rb + r;
      const float iv = sigmoidf_(acc[fm][0][r] + bf2f_(ep[idx].x));
      const float fv = sigmoidf_(acc[fm][1][r] + bf2f_(ep[idx].y));
      const float gv = tanhf_(acc[fm][2][r] + bf2f_(ep[idx].z));
      const float ov = sigmoidf_(acc[fm][3][r] + bf2f_(ep[idx].w));
      const float cv = fv * cold[idx] + iv * gv;
      cbuf[(size_t)row * HID_ + hcol] = cv;
      const float hval = ov * tanhf_(cv);
      const __hip_bfloat16 hb = __float2bfloat16(hval);
      const int hsw = (hcol & ~63) | ((hcol & 63) ^ ((row & 7) << 3));
      hnext[(size_t)row * HID_ + hsw] = hb;
      if (last) hfin[(size_t)row * HID_ + hcol] = hb;
    }
  }
}

// fp32 -> bf16 flat convert
__global__ __launch_bounds__(256) void conv_bf16_k(const float* __restrict__ in,
                                                   __hip_bfloat16* __restrict__ out, int n4) {
  const int i = blockIdx.x * 256 + threadIdx.x;
  if (i >= n4) return;
  const float4 v = ((const float4*)in)[i];
  const int o = i * 4;
  out[o + 0] = __float2bfloat16(v.x);
  out[o + 1] = __float2bfloat16(v.y);
  out[o + 2] = __float2bfloat16(v.z);
  out[o + 3] = __float2bfloat16(v.w);
}

// in[R][C] fp32 -> out[C][R] bf16; PERM: gate-interleave out-rows (4h+g);
// SWZ: XOR-swizzle k (cols of out) per 64-group by out-row&7.
template <bool PERM, bool SWZ>
__global__ __launch_bounds__(256) void transpose_conv(const float* __restrict__ in,
                                                      __hip_bfloat16* __restrict__ out,
                                                      int R, int C) {
  __shared__ float tile[32][33];
  const int c0 = blockIdx.x * 32, r0 = blockIdx.y * 32;
  const int tx = threadIdx.x, ty = threadIdx.y;  // 32x8
#pragma unroll
  for (int i = 0; i < 4; ++i) {
    const int r = r0 + ty + i * 8, cc = c0 + tx;
    tile[ty + i * 8][tx] = (r < R && cc < C) ? in[(size_t)r * C + cc] : 0.f;
  }
  __syncthreads();
#pragma unroll
  for (int i = 0; i < 4; ++i) {
    const int ro = c0 + ty + i * 8, co = r0 + tx;
    if (ro < C && co < R) {
      const int n = PERM ? ((ro & 1023) * 4 + (ro >> 10)) : ro;
      int k = co;
      if (SWZ) k = (k & ~63) | ((k & 63) ^ ((n & 7) << 3));
      out[(size_t)n * R + k] = __float2bfloat16(tile[tx][ty + i * 8]);
    }
  }
}

// bP[4h+g] = bx[g*1024+h] + bh[g*1024+h]
__global__ __launch_bounds__(256) void bias_perm(const float* __restrict__ bx,
                                                 const float* __restrict__ bh,
                                                 float* __restrict__ bP) {
  const int n = blockIdx.x * 256 + threadIdx.x;
  if (n >= G4_) return;
  const int h = n >> 2, g = n & 3;
  bP[n] = bx[g * HID_ + h] + bh[g * HID_ + h];
}

extern "C" void kernel_launch(void* const* d_in, const int* in_sizes, int n_in,
                              void* d_out, int out_size, void* d_ws, size_t ws_size,
                              hipStream_t stream) {
  const int* X = (const int*)d_in[0];
  const float* C = (const float*)d_in[1];
  const float* Wx = (const float*)d_in[2];
  const float* bx = (const float*)d_in[3];
  const float* Wh = (const float*)d_in[4];
  const float* bh = (const float*)d_in[5];
  const float* Wo = (const float*)d_in[6];
  const float* bo = (const float*)d_in[7];
  float* out = (float*)d_out;

  char* p = (char*)d_ws;
  const size_t szCb  = (size_t)NCLS_ * EMB_ * 2;   // Cb, reused for Wot
  const size_t szWxt = (size_t)G4_ * EMB_ * 2;
  const size_t szWhs = (size_t)G4_ * HID_ * 2;
  const size_t szEpr = (size_t)NCLS_ * G4_ * 2;
  const size_t szH   = (size_t)BATCH_ * HID_ * 2;  // x3: hA, hB, hfin
  const size_t szC   = (size_t)BATCH_ * HID_ * 4;
  const size_t szBp  = (size_t)G4_ * 4;
  if (ws_size < szCb + szWxt + szWhs + szEpr + 3 * szH + szC + szBp) return;

  __hip_bfloat16* Cb   = (__hip_bfloat16*)p; p += szCb;
  __hip_bfloat16* WxtP = (__hip_bfloat16*)p; p += szWxt;
  __hip_bfloat16* Whs  = (__hip_bfloat16*)p; p += szWhs;
  __hip_bfloat16* Epr  = (__hip_bfloat16*)p; p += szEpr;
  __hip_bfloat16* hA   = (__hip_bfloat16*)p; p += szH;
  __hip_bfloat16* hB   = (__hip_bfloat16*)p; p += szH;
  __hip_bfloat16* hfin = (__hip_bfloat16*)p; p += szH;
  float* cbuf          = (float*)p;          p += szC;
  float* bP            = (float*)p;          p += szBp;

  // 1. C -> bf16
  {
    const int n4 = NCLS_ * EMB_ / 4;
    conv_bf16_k<<<(n4 + 255) / 256, 256, 0, stream>>>(C, Cb, n4);
  }
  // 2. Wx -> [4096][1024] gate-interleaved rows (for E_proj GEMM)
  transpose_conv<true, false><<<dim3(G4_ / 32, EMB_ / 32), dim3(32, 8), 0, stream>>>(
      Wx, WxtP, EMB_, G4_);
  // 3. Wh -> [4096][1024] plain rows, k-swizzled (for lstm_step)
  transpose_conv<false, true><<<dim3(G4_ / 32, HID_ / 32), dim3(32, 8), 0, stream>>>(
      Wh, Whs, HID_, G4_);
  // 4. permuted bias
  bias_perm<<<G4_ / 256, 256, 0, stream>>>(bx, bh, bP);

  // 5. Epr[V][4096] = C @ Wx (gate-interleaved cols) + (bx+bh)
  gemm_bt<0><<<dim3(G4_ / 128, (NCLS_ + 127) / 128), 256, 0, stream>>>(
      Cb, WxtP, nullptr, Epr, NCLS_, G4_, EMB_, G4_, bP);

  // 6. zero initial state
  hipMemsetAsync(hA, 0, szH, stream);
  hipMemsetAsync(cbuf, 0, szC, stream);

  // 7. 128 fused LSTM steps (ping-pong h buffers)
  for (int t = 0; t < SEQ_; ++t) {
    const __hip_bfloat16* hp = (t & 1) ? hB : hA;
    __hip_bfloat16* hn = (t & 1) ? hA : hB;
    lstm_step<<<256, 256, 0, stream>>>(hp, Whs, Epr, X, cbuf, hn, hfin, t,
                                       (int)(t == SEQ_ - 1));
  }

  // 8. W_out^T (plain) into Cb region (dead after step 5)
  __hip_bfloat16* Wot = Cb;
  transpose_conv<false, false><<<dim3((NCLS_ + 31) / 32, HID_ / 32), dim3(32, 8), 0,
                                 stream>>>(Wo, Wot, HID_, NCLS_);

  // 9. logits = hfin @ W_out + b_out
  gemm_bt<2><<<dim3((NCLS_ + 127) / 128, BATCH_ / 128), 256, 0, stream>>>(
      hfin, Wot, out, nullptr, BATCH_, NCLS_, HID_, NCLS_, bo);
}

// Round 4
// 3307.003 us; speedup vs baseline: 3.9689x; 1.2153x over previous
//
#include <hip/hip_runtime.h>
#include <hip/hip_bf16.h>

#define SEQ_   128
#define NCLS_  50257
#define EMB_   1024
#define HID_   1024
#define BATCH_ 1024
#define G4_    4096

typedef __attribute__((ext_vector_type(8))) short short8;
typedef __attribute__((ext_vector_type(4))) float f32x4;

__device__ __forceinline__ void async_copy16(void* lds, const void* g) {
  __builtin_amdgcn_global_load_lds(
      (const __attribute__((address_space(1))) void*)g,
      (__attribute__((address_space(3))) void*)lds, 16, 0, 0);
}

__device__ __forceinline__ void mfma_acc(f32x4& c, const short8& a, const short8& b) {
  asm("v_mfma_f32_16x16x32_bf16 %0, %1, %2, %0" : "+v"(c) : "v"(a), "v"(b));
}

__device__ __forceinline__ float sigmoidf_(float x) {
  return 1.f / (1.f + __expf(-x));
}
__device__ __forceinline__ float tanhf_(float x) {
  x = fminf(12.f, fmaxf(-12.f, x));
  float e = __expf(2.f * x);
  return (e - 1.f) / (e + 1.f);
}
__device__ __forceinline__ float bf2f_(ushort u) {
  return __uint_as_float(((unsigned int)u) << 16);
}

// ---------------------------------------------------------------------------
// MFMA GEMM: C[M,N] = A[M,K] x Bt[N,K] (both bf16, rows k-XOR-swizzled:
// within each 64-elem k-group, 8-elem chunk index ^= row&7). BK=64,
// double-buffered LDS (A0|A1|B0|B1 x 16 KB), counted vmcnt(8).
// EPI 0: outB = bf16(acc + bias0[col])   (E_proj; bias pre-permuted)
// EPI 2: outF = acc + bias0[col]         (logits)
// ---------------------------------------------------------------------------
template <int EPI>
__global__ __launch_bounds__(256) void gemm_bt(
    const __hip_bfloat16* __restrict__ A, const __hip_bfloat16* __restrict__ Bt,
    float* __restrict__ outF, __hip_bfloat16* __restrict__ outB,
    int Mreal, int Nreal, int K, long ostride,
    const float* __restrict__ bias0) {
  __shared__ __align__(16) char smem[65536];

  const int tid = threadIdx.x;
  const int lane = tid & 63;
  const int w = tid >> 6;
  const int wm = w >> 1;
  const int wn = w & 1;
  const int m0 = blockIdx.y * 128;
  const int n0 = blockIdx.x * 128;

  const int fr = lane & 15;
  const int kb = (lane >> 4) * 16;
  const int swz = (fr & 7) << 4;

  f32x4 acc[4][4];
#pragma unroll
  for (int i = 0; i < 4; ++i)
#pragma unroll
    for (int j = 0; j < 4; ++j) acc[i][j] = (f32x4)(0.0f);

  auto STAGE = [&](int kc, int b) {
#pragma unroll
    for (int q = 0; q < 8; ++q) {
      const int ridx = (q & 3) * 256 + tid;   // 0..1023
      const int row = ridx >> 3;              // 0..127
      const int ch = ridx & 7;
      const __hip_bfloat16* src;
      char* dst;
      if (q < 4) {
        long ar = m0 + row; if (ar >= Mreal) ar = Mreal - 1;
        src = A + ar * (long)K + kc * 64 + ch * 8;
        dst = smem + b * 16384 + ridx * 16;
      } else {
        long br = n0 + row; if (br >= Nreal) br = Nreal - 1;
        src = Bt + br * (long)K + kc * 64 + ch * 8;
        dst = smem + 32768 + b * 16384 + ridx * 16;
      }
      async_copy16(dst, src);
    }
  };

  const int KC = K >> 6;
  STAGE(0, 0);
  for (int kc = 0; kc < KC; ++kc) {
    const int b = kc & 1;
    if (kc + 1 < KC) {
      STAGE(kc + 1, b ^ 1);
      asm volatile("s_waitcnt vmcnt(8)" ::: "memory");
    } else {
      asm volatile("s_waitcnt vmcnt(0)" ::: "memory");
    }
    __builtin_amdgcn_s_barrier();
    __builtin_amdgcn_sched_barrier(0);

    short8 aR[2][4], bR[2][4];
#pragma unroll
    for (int kk = 0; kk < 2; ++kk)
#pragma unroll
      for (int f = 0; f < 4; ++f) {
        aR[kk][f] = *(const short8*)(smem + b * 16384 +
                     (wm * 64 + f * 16 + fr) * 128 + ((kk * 64 + kb) ^ swz));
        bR[kk][f] = *(const short8*)(smem + 32768 + b * 16384 +
                     (wn * 64 + f * 16 + fr) * 128 + ((kk * 64 + kb) ^ swz));
      }
#pragma unroll
    for (int fm = 0; fm < 4; ++fm)
#pragma unroll
      for (int fn = 0; fn < 4; ++fn) {
        mfma_acc(acc[fm][fn], aR[0][fm], bR[0][fn]);
        mfma_acc(acc[fm][fn], aR[1][fm], bR[1][fn]);
      }
    __builtin_amdgcn_sched_barrier(0);
    __builtin_amdgcn_s_barrier();
  }

  const int cn = lane & 15;
  const int rb = (lane >> 4) * 4;
#pragma unroll
  for (int fn = 0; fn < 4; ++fn) {
    const int col = n0 + wn * 64 + fn * 16 + cn;
    const float badd = (col < Nreal) ? bias0[col] : 0.f;
#pragma unroll
    for (int fm = 0; fm < 4; ++fm) {
#pragma unroll
      for (int r = 0; r < 4; ++r) {
        const int row = m0 + wm * 64 + fm * 16 + rb + r;
        const float v = acc[fm][fn][r] + badd;
        if (EPI == 0) {
          if (row < Mreal) outB[(long)row * ostride + col] = __float2bfloat16(v);
        } else {
          if (col < Nreal && row < Mreal) outF[(long)row * ostride + col] = v;
        }
      }
    }
  }
}

// ---------------------------------------------------------------------------
// Fused LSTM step. Grid 256 (8 mt x 32 ht), 256 threads (4 waves).
// Block: 128 batch-rows x 32 h x 4 gates (col = 4h+g). fn indexes the GATE,
// so each lane holds i,f,g,o for its (row,h) -> cell fused, no exchange.
// BK=64 double-buffered staging, counted vmcnt(8). hprev/Whs k-swizzled.
// Token/Eps/c loads issued BEFORE the K-loop to hide gather latency.
// ---------------------------------------------------------------------------
__global__ __launch_bounds__(256) void lstm_step(
    const __hip_bfloat16* __restrict__ hprev,   // [1024][1024] swizzled
    const __hip_bfloat16* __restrict__ Whs,     // [4096][1024] swizzled
    const __hip_bfloat16* __restrict__ Epr,     // [V][4096] col=4h+g, plain
    const int* __restrict__ X,
    float* __restrict__ cbuf,                   // [1024][1024] f32
    __hip_bfloat16* __restrict__ hnext,         // swizzled
    __hip_bfloat16* __restrict__ hfin,          // swizzled (last step only)
    int t, int last) {
  __shared__ __align__(16) char smem[65536];    // A0|A1|B0|B1 x 16 KB

  const int tid = threadIdx.x;
  const int lane = tid & 63;
  const int w = tid >> 6;
  const int wm = w >> 1;
  const int wn = w & 1;
  const int bid = blockIdx.x;
  const int xcd = bid & 7;
  const int j = bid >> 3;
  const int ht = xcd * 4 + (j & 3);   // same ht group stays on one XCD
  const int mt = j >> 2;
  const int m0 = mt * 128;
  const int h0 = ht * 32;

  const int fr = lane & 15;
  const int cn = lane & 15;
  const int rb = (lane >> 4) * 4;
  const int kb = (lane >> 4) * 16;
  const int swz = (fr & 7) << 4;
  const int hcol = h0 + wn * 16 + cn;

  // ---- prefetch: tokens -> Eps rows (i,f,g,o interleaved) + c state
  int tok[16];
#pragma unroll
  for (int fm = 0; fm < 4; ++fm)
#pragma unroll
    for (int r = 0; r < 4; ++r) {
      const int row = m0 + wm * 64 + fm * 16 + rb + r;
      tok[fm * 4 + r] = X[row * SEQ_ + t];
    }
  ushort4 ep[16];
  float cold[16];
#pragma unroll
  for (int fm = 0; fm < 4; ++fm)
#pragma unroll
    for (int r = 0; r < 4; ++r) {
      const int idx = fm * 4 + r;
      const int row = m0 + wm * 64 + fm * 16 + rb + r;
      ep[idx] = *(const ushort4*)(Epr + (size_t)tok[idx] * G4_ + 4 * hcol);
      cold[idx] = cbuf[(size_t)row * HID_ + hcol];
    }

  f32x4 acc[4][4];  // [fm][gate]
#pragma unroll
  for (int i = 0; i < 4; ++i)
#pragma unroll
    for (int g = 0; g < 4; ++g) acc[i][g] = (f32x4)(0.0f);

  auto STAGE = [&](int kc, int b) {
#pragma unroll
    for (int q = 0; q < 8; ++q) {
      const int ridx = (q & 3) * 256 + tid;   // 0..1023
      const int row = ridx >> 3;              // 0..127
      const int ch = ridx & 7;
      const __hip_bfloat16* src;
      char* dst;
      if (q < 4) {
        src = hprev + (size_t)(m0 + row) * HID_ + kc * 64 + ch * 8;
        dst = smem + b * 16384 + ridx * 16;
      } else {
        const int g = row >> 5, hh = row & 31;
        src = Whs + (size_t)(g * 1024 + h0 + hh) * HID_ + kc * 64 + ch * 8;
        dst = smem + 32768 + b * 16384 + ridx * 16;
      }
      async_copy16(dst, src);
    }
  };

  STAGE(0, 0);
  for (int kc = 0; kc < 16; ++kc) {
    const int b = kc & 1;
    if (kc < 15) {
      STAGE(kc + 1, b ^ 1);
      asm volatile("s_waitcnt vmcnt(8)" ::: "memory");
    } else {
      asm volatile("s_waitcnt vmcnt(0)" ::: "memory");
    }
    __builtin_amdgcn_s_barrier();
    __builtin_amdgcn_sched_barrier(0);

    short8 aR[2][4], bR[2][4];
#pragma unroll
    for (int kk = 0; kk < 2; ++kk)
#pragma unroll
      for (int f = 0; f < 4; ++f) {
        aR[kk][f] = *(const short8*)(smem + b * 16384 +
                     (wm * 64 + f * 16 + fr) * 128 + ((kk * 64 + kb) ^ swz));
        bR[kk][f] = *(const short8*)(smem + 32768 + b * 16384 +
                     (f * 32 + wn * 16 + fr) * 128 + ((kk * 64 + kb) ^ swz));
      }
#pragma unroll
    for (int fm = 0; fm < 4; ++fm)
#pragma unroll
      for (int g = 0; g < 4; ++g) {
        mfma_acc(acc[fm][g], aR[0][fm], bR[0][g]);
        mfma_acc(acc[fm][g], aR[1][fm], bR[1][g]);
      }
    __builtin_amdgcn_sched_barrier(0);
    __builtin_amdgcn_s_barrier();
  }

  // ---- fused cell epilogue
#pragma unroll
  for (int fm = 0; fm < 4; ++fm) {
#pragma unroll
    for (int r = 0; r < 4; ++r) {
      const int idx = fm * 4 + r;
      const int row = m0 + wm * 64 + fm * 16 + rb + r;
      const float iv = sigmoidf_(acc[fm][0][r] + bf2f_(ep[idx].x));
      const float fv = sigmoidf_(acc[fm][1][r] + bf2f_(ep[idx].y));
      const float gv = tanhf_(acc[fm][2][r] + bf2f_(ep[idx].z));
      const float ov = sigmoidf_(acc[fm][3][r] + bf2f_(ep[idx].w));
      const float cv = fv * cold[idx] + iv * gv;
      cbuf[(size_t)row * HID_ + hcol] = cv;
      const float hval = ov * tanhf_(cv);
      const __hip_bfloat16 hb = __float2bfloat16(hval);
      const int hsw = (hcol & ~63) | ((hcol & 63) ^ ((row & 7) << 3));
      hnext[(size_t)row * HID_ + hsw] = hb;
      if (last) hfin[(size_t)row * HID_ + hsw] = hb;
    }
  }
}

// fp32 -> bf16 flat convert; SWZ: k-XOR-swizzle per 64-col group (1024 cols)
template <bool SWZ>
__global__ __launch_bounds__(256) void conv_bf16_k(const float* __restrict__ in,
                                                   __hip_bfloat16* __restrict__ out, int n4) {
  const int i = blockIdx.x * 256 + threadIdx.x;
  if (i >= n4) return;
  const float4 v = ((const float4*)in)[i];
  int o = i * 4;
  if (SWZ) {
    const int row = o >> 10, col = o & 1023;
    const int cs = (col & ~63) | ((col & 63) ^ ((row & 7) << 3));
    o = (o & ~1023) | cs;
  }
  out[o + 0] = __float2bfloat16(v.x);
  out[o + 1] = __float2bfloat16(v.y);
  out[o + 2] = __float2bfloat16(v.z);
  out[o + 3] = __float2bfloat16(v.w);
}

// in[R][C] fp32 -> out[C][R] bf16; PERM: gate-interleave out-rows (4h+g);
// SWZ: XOR-swizzle k (cols of out) per 64-group by out-row&7.
template <bool PERM, bool SWZ>
__global__ __launch_bounds__(256) void transpose_conv(const float* __restrict__ in,
                                                      __hip_bfloat16* __restrict__ out,
                                                      int R, int C) {
  __shared__ float tile[32][33];
  const int c0 = blockIdx.x * 32, r0 = blockIdx.y * 32;
  const int tx = threadIdx.x, ty = threadIdx.y;  // 32x8
#pragma unroll
  for (int i = 0; i < 4; ++i) {
    const int r = r0 + ty + i * 8, cc = c0 + tx;
    tile[ty + i * 8][tx] = (r < R && cc < C) ? in[(size_t)r * C + cc] : 0.f;
  }
  __syncthreads();
#pragma unroll
  for (int i = 0; i < 4; ++i) {
    const int ro = c0 + ty + i * 8, co = r0 + tx;
    if (ro < C && co < R) {
      const int n = PERM ? ((ro & 1023) * 4 + (ro >> 10)) : ro;
      int k = co;
      if (SWZ) k = (k & ~63) | ((k & 63) ^ ((n & 7) << 3));
      out[(size_t)n * R + k] = __float2bfloat16(tile[tx][ty + i * 8]);
    }
  }
}

// bP[4h+g] = bx[g*1024+h] + bh[g*1024+h]
__global__ __launch_bounds__(256) void bias_perm(const float* __restrict__ bx,
                                                 const float* __restrict__ bh,
                                                 float* __restrict__ bP) {
  const int n = blockIdx.x * 256 + threadIdx.x;
  if (n >= G4_) return;
  const int h = n >> 2, g = n & 3;
  bP[n] = bx[g * HID_ + h] + bh[g * HID_ + h];
}

extern "C" void kernel_launch(void* const* d_in, const int* in_sizes, int n_in,
                              void* d_out, int out_size, void* d_ws, size_t ws_size,
                              hipStream_t stream) {
  const int* X = (const int*)d_in[0];
  const float* C = (const float*)d_in[1];
  const float* Wx = (const float*)d_in[2];
  const float* bx = (const float*)d_in[3];
  const float* Wh = (const float*)d_in[4];
  const float* bh = (const float*)d_in[5];
  const float* Wo = (const float*)d_in[6];
  const float* bo = (const float*)d_in[7];
  float* out = (float*)d_out;

  char* p = (char*)d_ws;
  const size_t szCb  = (size_t)NCLS_ * EMB_ * 2;   // Cb, reused for Wot
  const size_t szWxt = (size_t)G4_ * EMB_ * 2;
  const size_t szWhs = (size_t)G4_ * HID_ * 2;
  const size_t szEpr = (size_t)NCLS_ * G4_ * 2;
  const size_t szH   = (size_t)BATCH_ * HID_ * 2;  // x3: hA, hB, hfin
  const size_t szC   = (size_t)BATCH_ * HID_ * 4;
  const size_t szBp  = (size_t)G4_ * 4;
  if (ws_size < szCb + szWxt + szWhs + szEpr + 3 * szH + szC + szBp) return;

  __hip_bfloat16* Cb   = (__hip_bfloat16*)p; p += szCb;
  __hip_bfloat16* WxtP = (__hip_bfloat16*)p; p += szWxt;
  __hip_bfloat16* Whs  = (__hip_bfloat16*)p; p += szWhs;
  __hip_bfloat16* Epr  = (__hip_bfloat16*)p; p += szEpr;
  __hip_bfloat16* hA   = (__hip_bfloat16*)p; p += szH;
  __hip_bfloat16* hB   = (__hip_bfloat16*)p; p += szH;
  __hip_bfloat16* hfin = (__hip_bfloat16*)p; p += szH;
  float* cbuf          = (float*)p;          p += szC;
  float* bP            = (float*)p;          p += szBp;

  // 1. C -> bf16, k-swizzled (A operand of E_proj GEMM)
  {
    const int n4 = NCLS_ * EMB_ / 4;
    conv_bf16_k<true><<<(n4 + 255) / 256, 256, 0, stream>>>(C, Cb, n4);
  }
  // 2. Wx -> [4096][1024] gate-interleaved rows, k-swizzled
  transpose_conv<true, true><<<dim3(G4_ / 32, EMB_ / 32), dim3(32, 8), 0, stream>>>(
      Wx, WxtP, EMB_, G4_);
  // 3. Wh -> [4096][1024] plain rows, k-swizzled (for lstm_step)
  transpose_conv<false, true><<<dim3(G4_ / 32, HID_ / 32), dim3(32, 8), 0, stream>>>(
      Wh, Whs, HID_, G4_);
  // 4. permuted bias
  bias_perm<<<G4_ / 256, 256, 0, stream>>>(bx, bh, bP);

  // 5. Epr[V][4096] = C @ Wx (gate-interleaved cols) + (bx+bh), plain layout
  gemm_bt<0><<<dim3(G4_ / 128, (NCLS_ + 127) / 128), 256, 0, stream>>>(
      Cb, WxtP, nullptr, Epr, NCLS_, G4_, EMB_, G4_, bP);

  // 6. zero initial state (zeros are swizzle-invariant)
  hipMemsetAsync(hA, 0, szH, stream);
  hipMemsetAsync(cbuf, 0, szC, stream);

  // 7. 128 fused LSTM steps (ping-pong h buffers)
  for (int t = 0; t < SEQ_; ++t) {
    const __hip_bfloat16* hp = (t & 1) ? hB : hA;
    __hip_bfloat16* hn = (t & 1) ? hA : hB;
    lstm_step<<<256, 256, 0, stream>>>(hp, Whs, Epr, X, cbuf, hn, hfin, t,
                                       (int)(t == SEQ_ - 1));
  }

  // 8. W_out^T, k-swizzled, into Cb region (dead after step 5)
  __hip_bfloat16* Wot = Cb;
  transpose_conv<false, true><<<dim3((NCLS_ + 31) / 32, HID_ / 32), dim3(32, 8), 0,
                                stream>>>(Wo, Wot, HID_, NCLS_);

  // 9. logits = hfin @ W_out + b_out
  gemm_bt<2><<<dim3((NCLS_ + 127) / 128, BATCH_ / 128), 256, 0, stream>>>(
      hfin, Wot, out, nullptr, BATCH_, NCLS_, HID_, NCLS_, bo);
}

// Round 5
// 3305.621 us; speedup vs baseline: 3.9706x; 1.0004x over previous
//
#include <hip/hip_runtime.h>
#include <hip/hip_bf16.h>

#define SEQ_   128
#define NCLS_  50257
#define EMB_   1024
#define HID_   1024
#define BATCH_ 1024
#define G4_    4096

typedef __attribute__((ext_vector_type(8))) short short8;
typedef __attribute__((ext_vector_type(4))) float f32x4;

__device__ __forceinline__ void async_copy16(void* lds, const void* g) {
  __builtin_amdgcn_global_load_lds(
      (const __attribute__((address_space(1))) void*)g,
      (__attribute__((address_space(3))) void*)lds, 16, 0, 0);
}

__device__ __forceinline__ void mfma_acc(f32x4& c, const short8& a, const short8& b) {
  asm("v_mfma_f32_16x16x32_bf16 %0, %1, %2, %0" : "+v"(c) : "v"(a), "v"(b));
}

__device__ __forceinline__ float sigmoidf_(float x) {
  return 1.f / (1.f + __expf(-x));
}
__device__ __forceinline__ float tanhf_(float x) {
  x = fminf(12.f, fmaxf(-12.f, x));
  float e = __expf(2.f * x);
  return (e - 1.f) / (e + 1.f);
}
__device__ __forceinline__ float bf2f_(ushort u) {
  return __uint_as_float(((unsigned int)u) << 16);
}

// ---------------------------------------------------------------------------
// MFMA GEMM: C[M,N] = A[M,K] x Bt[N,K] (both bf16, rows k-XOR-swizzled:
// within each 64-elem k-group, 8-elem chunk index ^= row&7). BK=64,
// double-buffered LDS (A0|A1|B0|B1 x 16 KB), counted vmcnt(8).
// EPI 0: outB = bf16(acc + bias0[col])   (E_proj; bias pre-permuted)
// EPI 2: outF = acc + bias0[col]         (logits)
// ---------------------------------------------------------------------------
template <int EPI>
__global__ __launch_bounds__(256) void gemm_bt(
    const __hip_bfloat16* __restrict__ A, const __hip_bfloat16* __restrict__ Bt,
    float* __restrict__ outF, __hip_bfloat16* __restrict__ outB,
    int Mreal, int Nreal, int K, long ostride,
    const float* __restrict__ bias0) {
  __shared__ __align__(16) char smem[65536];

  const int tid = threadIdx.x;
  const int lane = tid & 63;
  const int w = tid >> 6;
  const int wm = w >> 1;
  const int wn = w & 1;
  const int m0 = blockIdx.y * 128;
  const int n0 = blockIdx.x * 128;

  const int fr = lane & 15;
  const int kb = (lane >> 4) * 16;
  const int swz = (fr & 7) << 4;

  f32x4 acc[4][4];
#pragma unroll
  for (int i = 0; i < 4; ++i)
#pragma unroll
    for (int j = 0; j < 4; ++j) acc[i][j] = (f32x4)(0.0f);

  auto STAGE = [&](int kc, int b) {
#pragma unroll
    for (int q = 0; q < 8; ++q) {
      const int ridx = (q & 3) * 256 + tid;   // 0..1023
      const int row = ridx >> 3;              // 0..127
      const int ch = ridx & 7;
      const __hip_bfloat16* src;
      char* dst;
      if (q < 4) {
        long ar = m0 + row; if (ar >= Mreal) ar = Mreal - 1;
        src = A + ar * (long)K + kc * 64 + ch * 8;
        dst = smem + b * 16384 + ridx * 16;
      } else {
        long br = n0 + row; if (br >= Nreal) br = Nreal - 1;
        src = Bt + br * (long)K + kc * 64 + ch * 8;
        dst = smem + 32768 + b * 16384 + ridx * 16;
      }
      async_copy16(dst, src);
    }
  };

  const int KC = K >> 6;
  STAGE(0, 0);
  for (int kc = 0; kc < KC; ++kc) {
    const int b = kc & 1;
    if (kc + 1 < KC) {
      STAGE(kc + 1, b ^ 1);
      asm volatile("s_waitcnt vmcnt(8)" ::: "memory");
    } else {
      asm volatile("s_waitcnt vmcnt(0)" ::: "memory");
    }
    __builtin_amdgcn_s_barrier();
    __builtin_amdgcn_sched_barrier(0);

    short8 aR[2][4], bR[2][4];
#pragma unroll
    for (int kk = 0; kk < 2; ++kk)
#pragma unroll
      for (int f = 0; f < 4; ++f) {
        aR[kk][f] = *(const short8*)(smem + b * 16384 +
                     (wm * 64 + f * 16 + fr) * 128 + ((kk * 64 + kb) ^ swz));
        bR[kk][f] = *(const short8*)(smem + 32768 + b * 16384 +
                     (wn * 64 + f * 16 + fr) * 128 + ((kk * 64 + kb) ^ swz));
      }
#pragma unroll
    for (int fm = 0; fm < 4; ++fm)
#pragma unroll
      for (int fn = 0; fn < 4; ++fn) {
        mfma_acc(acc[fm][fn], aR[0][fm], bR[0][fn]);
        mfma_acc(acc[fm][fn], aR[1][fm], bR[1][fn]);
      }
    __builtin_amdgcn_sched_barrier(0);
    __builtin_amdgcn_s_barrier();
  }

  const int cn = lane & 15;
  const int rb = (lane >> 4) * 4;
#pragma unroll
  for (int fn = 0; fn < 4; ++fn) {
    const int col = n0 + wn * 64 + fn * 16 + cn;
    const float badd = (col < Nreal) ? bias0[col] : 0.f;
#pragma unroll
    for (int fm = 0; fm < 4; ++fm) {
#pragma unroll
      for (int r = 0; r < 4; ++r) {
        const int row = m0 + wm * 64 + fm * 16 + rb + r;
        const float v = acc[fm][fn][r] + badd;
        if (EPI == 0) {
          if (row < Mreal) outB[(long)row * ostride + col] = __float2bfloat16(v);
        } else {
          if (col < Nreal && row < Mreal) outF[(long)row * ostride + col] = v;
        }
      }
    }
  }
}

// ---------------------------------------------------------------------------
// Fused LSTM step. Grid 256 (8 mt x 32 ht), 512 threads (8 waves).
// Block: 128 batch-rows x 32 h x 4 gates (col = 4h+g).
// Waves: (wm,wn) 2x2 output tiles (64 rows x 16 h x 4 gates) x kh 2 K-halves
// (K=512 each). fn indexes the GATE. K-half partials merged in LDS (gacc
// aliases dead staging buffers), then all 512 threads run the fused cell.
// BK=64 per half, double-buffered staging (128 KB dynamic LDS), vmcnt(8).
// hprev/Whs k-swizzled. Eps/c/token prefetched before the K-loop.
// ---------------------------------------------------------------------------
__global__ __launch_bounds__(512) void lstm_step(
    const __hip_bfloat16* __restrict__ hprev,   // [1024][1024] swizzled
    const __hip_bfloat16* __restrict__ Whs,     // [4096][1024] swizzled
    const __hip_bfloat16* __restrict__ Epr,     // [V][4096] col=4h+g, plain
    const int* __restrict__ X,
    float* __restrict__ cbuf,                   // [1024][1024] f32
    __hip_bfloat16* __restrict__ hnext,         // swizzled
    __hip_bfloat16* __restrict__ hfin,          // swizzled (last step only)
    int t, int last) {
  extern __shared__ __align__(16) char smem[];  // 128 KB: [A_h0|A_h1|B_h0|B_h1] x 2dbuf
  float* gacc = (float*)smem;                   // [128][132] f32, aliases staging

  const int tid = threadIdx.x;
  const int lane = tid & 63;
  const int w = tid >> 6;        // 0..7
  const int wm = (w >> 1) & 1;
  const int wn = w & 1;
  const int kh = w >> 2;         // K-half
  const int bid = blockIdx.x;
  const int xcd = bid & 7;
  const int j = bid >> 3;
  const int ht = xcd * 4 + (j & 3);   // same ht group stays on one XCD
  const int mt = j >> 2;
  const int m0 = mt * 128;
  const int h0 = ht * 32;

  const int fr = lane & 15;
  const int kb = (lane >> 4) * 16;
  const int swz = (fr & 7) << 4;

  // ---- cell-phase mapping + prefetch (hides Eps gather under K-loop)
  const int crow = tid >> 2;          // 0..127
  const int hq = tid & 3;             // h quarter (8 h each)
  const int prow = m0 + crow;
  const int tok1 = X[prow * SEQ_ + t];
  ushort4 ep[8];
  float cold[8];
#pragma unroll
  for (int jj = 0; jj < 8; ++jj) {
    ep[jj] = *(const ushort4*)(Epr + (size_t)tok1 * G4_ + (h0 + hq * 8 + jj) * 4);
    cold[jj] = cbuf[(size_t)prow * HID_ + h0 + hq * 8 + jj];
  }

  f32x4 acc[4][4];  // [fm][gate]
#pragma unroll
  for (int i = 0; i < 4; ++i)
#pragma unroll
    for (int g = 0; g < 4; ++g) acc[i][g] = (f32x4)(0.0f);

  // staging: region = q>>1 (A_h0,A_h1,B_h0,B_h1), r = (q&1)*512+tid
  auto STAGE = [&](int kc, int b) {
#pragma unroll
    for (int q = 0; q < 8; ++q) {
      const int region = q >> 1;
      const int r = (q & 1) * 512 + tid;   // 0..1023
      const int row = r >> 3;              // 0..127
      const int ch = r & 7;
      const __hip_bfloat16* src;
      if (region < 2) {
        src = hprev + (size_t)(m0 + row) * HID_ + region * 512 + kc * 64 + ch * 8;
      } else {
        const int g = row >> 5, hh = row & 31;
        src = Whs + (size_t)(g * 1024 + h0 + hh) * HID_ + (region - 2) * 512 +
              kc * 64 + ch * 8;
      }
      async_copy16(smem + region * 32768 + b * 16384 + r * 16, src);
    }
  };

  STAGE(0, 0);
  for (int kc = 0; kc < 8; ++kc) {
    const int b = kc & 1;
    if (kc < 7) {
      STAGE(kc + 1, b ^ 1);
      asm volatile("s_waitcnt vmcnt(8)" ::: "memory");
    } else {
      asm volatile("s_waitcnt vmcnt(0)" ::: "memory");
    }
    __builtin_amdgcn_s_barrier();
    __builtin_amdgcn_sched_barrier(0);

    const char* baseA = smem + kh * 32768 + b * 16384;
    const char* baseB = smem + 65536 + kh * 32768 + b * 16384;
    short8 aR[2][4], bR[2][4];
#pragma unroll
    for (int kk = 0; kk < 2; ++kk)
#pragma unroll
      for (int f = 0; f < 4; ++f) {
        aR[kk][f] = *(const short8*)(baseA + (wm * 64 + f * 16 + fr) * 128 +
                                     ((kk * 64 + kb) ^ swz));
        bR[kk][f] = *(const short8*)(baseB + (f * 32 + wn * 16 + fr) * 128 +
                                     ((kk * 64 + kb) ^ swz));
      }
#pragma unroll
    for (int fm = 0; fm < 4; ++fm)
#pragma unroll
      for (int g = 0; g < 4; ++g) {
        mfma_acc(acc[fm][g], aR[0][fm], bR[0][g]);
        mfma_acc(acc[fm][g], aR[1][fm], bR[1][g]);
      }
    __builtin_amdgcn_sched_barrier(0);
    __builtin_amdgcn_s_barrier();
  }

  // ---- merge K-half partials in LDS (gacc col = 4*h_local + gate)
  const int cn = lane & 15;
  const int rb = (lane >> 4) * 4;
  if (kh == 0) {
#pragma unroll
    for (int fm = 0; fm < 4; ++fm)
#pragma unroll
      for (int g = 0; g < 4; ++g)
#pragma unroll
        for (int r = 0; r < 4; ++r)
          gacc[(wm * 64 + fm * 16 + rb + r) * 132 + (wn * 16 + cn) * 4 + g] =
              acc[fm][g][r];
  }
  __syncthreads();
  if (kh == 1) {
#pragma unroll
    for (int fm = 0; fm < 4; ++fm)
#pragma unroll
      for (int g = 0; g < 4; ++g)
#pragma unroll
        for (int r = 0; r < 4; ++r)
          gacc[(wm * 64 + fm * 16 + rb + r) * 132 + (wn * 16 + cn) * 4 + g] +=
              acc[fm][g][r];
  }
  __syncthreads();

  // ---- fused cell epilogue: thread = (crow, hq), 8 h each, all 4 gates local
  const float* gr = gacc + crow * 132 + hq * 32;
  f32x4 cnew0, cnew1;
  short8 hv;
#pragma unroll
  for (int jj = 0; jj < 8; ++jj) {
    const f32x4 g4 = *(const f32x4*)(gr + jj * 4);
    const float iv = sigmoidf_(g4[0] + bf2f_(ep[jj].x));
    const float fv = sigmoidf_(g4[1] + bf2f_(ep[jj].y));
    const float gv = tanhf_(g4[2] + bf2f_(ep[jj].z));
    const float ov = sigmoidf_(g4[3] + bf2f_(ep[jj].w));
    const float cv = fv * cold[jj] + iv * gv;
    if (jj < 4) cnew0[jj] = cv; else cnew1[jj - 4] = cv;
    const float hval = ov * tanhf_(cv);
    const __hip_bfloat16 hb = __float2bfloat16(hval);
    hv[jj] = *reinterpret_cast<const short*>(&hb);
  }
  float* cdst = cbuf + (size_t)prow * HID_ + h0 + hq * 8;
  *(f32x4*)cdst = cnew0;
  *(f32x4*)(cdst + 4) = cnew1;
  const int hcolb = h0 + hq * 8;
  const int hswb = (hcolb & ~63) | ((hcolb & 63) ^ ((prow & 7) << 3));
  *(short8*)(hnext + (size_t)prow * HID_ + hswb) = hv;
  if (last) *(short8*)(hfin + (size_t)prow * HID_ + hswb) = hv;
}

// fp32 -> bf16 flat convert; SWZ: k-XOR-swizzle per 64-col group (1024 cols)
template <bool SWZ>
__global__ __launch_bounds__(256) void conv_bf16_k(const float* __restrict__ in,
                                                   __hip_bfloat16* __restrict__ out, int n4) {
  const int i = blockIdx.x * 256 + threadIdx.x;
  if (i >= n4) return;
  const float4 v = ((const float4*)in)[i];
  int o = i * 4;
  if (SWZ) {
    const int row = o >> 10, col = o & 1023;
    const int cs = (col & ~63) | ((col & 63) ^ ((row & 7) << 3));
    o = (o & ~1023) | cs;
  }
  out[o + 0] = __float2bfloat16(v.x);
  out[o + 1] = __float2bfloat16(v.y);
  out[o + 2] = __float2bfloat16(v.z);
  out[o + 3] = __float2bfloat16(v.w);
}

// in[R][C] fp32 -> out[C][R] bf16; PERM: gate-interleave out-rows (4h+g);
// SWZ: XOR-swizzle k (cols of out) per 64-group by out-row&7.
template <bool PERM, bool SWZ>
__global__ __launch_bounds__(256) void transpose_conv(const float* __restrict__ in,
                                                      __hip_bfloat16* __restrict__ out,
                                                      int R, int C) {
  __shared__ float tile[32][33];
  const int c0 = blockIdx.x * 32, r0 = blockIdx.y * 32;
  const int tx = threadIdx.x, ty = threadIdx.y;  // 32x8
#pragma unroll
  for (int i = 0; i < 4; ++i) {
    const int r = r0 + ty + i * 8, cc = c0 + tx;
    tile[ty + i * 8][tx] = (r < R && cc < C) ? in[(size_t)r * C + cc] : 0.f;
  }
  __syncthreads();
#pragma unroll
  for (int i = 0; i < 4; ++i) {
    const int ro = c0 + ty + i * 8, co = r0 + tx;
    if (ro < C && co < R) {
      const int n = PERM ? ((ro & 1023) * 4 + (ro >> 10)) : ro;
      int k = co;
      if (SWZ) k = (k & ~63) | ((k & 63) ^ ((n & 7) << 3));
      out[(size_t)n * R + k] = __float2bfloat16(tile[tx][ty + i * 8]);
    }
  }
}

// bP[4h+g] = bx[g*1024+h] + bh[g*1024+h]
__global__ __launch_bounds__(256) void bias_perm(const float* __restrict__ bx,
                                                 const float* __restrict__ bh,
                                                 float* __restrict__ bP) {
  const int n = blockIdx.x * 256 + threadIdx.x;
  if (n >= G4_) return;
  const int h = n >> 2, g = n & 3;
  bP[n] = bx[g * HID_ + h] + bh[g * HID_ + h];
}

extern "C" void kernel_launch(void* const* d_in, const int* in_sizes, int n_in,
                              void* d_out, int out_size, void* d_ws, size_t ws_size,
                              hipStream_t stream) {
  const int* X = (const int*)d_in[0];
  const float* C = (const float*)d_in[1];
  const float* Wx = (const float*)d_in[2];
  const float* bx = (const float*)d_in[3];
  const float* Wh = (const float*)d_in[4];
  const float* bh = (const float*)d_in[5];
  const float* Wo = (const float*)d_in[6];
  const float* bo = (const float*)d_in[7];
  float* out = (float*)d_out;

  char* p = (char*)d_ws;
  const size_t szCb  = (size_t)NCLS_ * EMB_ * 2;   // Cb, reused for Wot
  const size_t szWxt = (size_t)G4_ * EMB_ * 2;
  const size_t szWhs = (size_t)G4_ * HID_ * 2;
  const size_t szEpr = (size_t)NCLS_ * G4_ * 2;
  const size_t szH   = (size_t)BATCH_ * HID_ * 2;  // x3: hA, hB, hfin
  const size_t szC   = (size_t)BATCH_ * HID_ * 4;
  const size_t szBp  = (size_t)G4_ * 4;
  if (ws_size < szCb + szWxt + szWhs + szEpr + 3 * szH + szC + szBp) return;

  __hip_bfloat16* Cb   = (__hip_bfloat16*)p; p += szCb;
  __hip_bfloat16* WxtP = (__hip_bfloat16*)p; p += szWxt;
  __hip_bfloat16* Whs  = (__hip_bfloat16*)p; p += szWhs;
  __hip_bfloat16* Epr  = (__hip_bfloat16*)p; p += szEpr;
  __hip_bfloat16* hA   = (__hip_bfloat16*)p; p += szH;
  __hip_bfloat16* hB   = (__hip_bfloat16*)p; p += szH;
  __hip_bfloat16* hfin = (__hip_bfloat16*)p; p += szH;
  float* cbuf          = (float*)p;          p += szC;
  float* bP            = (float*)p;          p += szBp;

  // 1. C -> bf16, k-swizzled (A operand of E_proj GEMM)
  {
    const int n4 = NCLS_ * EMB_ / 4;
    conv_bf16_k<true><<<(n4 + 255) / 256, 256, 0, stream>>>(C, Cb, n4);
  }
  // 2. Wx -> [4096][1024] gate-interleaved rows, k-swizzled
  transpose_conv<true, true><<<dim3(G4_ / 32, EMB_ / 32), dim3(32, 8), 0, stream>>>(
      Wx, WxtP, EMB_, G4_);
  // 3. Wh -> [4096][1024] plain rows, k-swizzled (for lstm_step)
  transpose_conv<false, true><<<dim3(G4_ / 32, HID_ / 32), dim3(32, 8), 0, stream>>>(
      Wh, Whs, HID_, G4_);
  // 4. permuted bias
  bias_perm<<<G4_ / 256, 256, 0, stream>>>(bx, bh, bP);

  // 5. Epr[V][4096] = C @ Wx (gate-interleaved cols) + (bx+bh), plain layout
  gemm_bt<0><<<dim3(G4_ / 128, (NCLS_ + 127) / 128), 256, 0, stream>>>(
      Cb, WxtP, nullptr, Epr, NCLS_, G4_, EMB_, G4_, bP);

  // 6. zero initial state (zeros are swizzle-invariant)
  hipMemsetAsync(hA, 0, szH, stream);
  hipMemsetAsync(cbuf, 0, szC, stream);

  // 7. 128 fused LSTM steps (ping-pong h buffers), 512 threads, 128 KB LDS
  for (int t = 0; t < SEQ_; ++t) {
    const __hip_bfloat16* hp = (t & 1) ? hB : hA;
    __hip_bfloat16* hn = (t & 1) ? hA : hB;
    lstm_step<<<256, 512, 131072, stream>>>(hp, Whs, Epr, X, cbuf, hn, hfin, t,
                                            (int)(t == SEQ_ - 1));
  }

  // 8. W_out^T, k-swizzled, into Cb region (dead after step 5)
  __hip_bfloat16* Wot = Cb;
  transpose_conv<false, true><<<dim3((NCLS_ + 31) / 32, HID_ / 32), dim3(32, 8), 0,
                                stream>>>(Wo, Wot, HID_, NCLS_);

  // 9. logits = hfin @ W_out + b_out
  gemm_bt<2><<<dim3((NCLS_ + 127) / 128, BATCH_ / 128), 256, 0, stream>>>(
      hfin, Wot, out, nullptr, BATCH_, NCLS_, HID_, NCLS_, bo);
}